// Round 2
// baseline (278.223 us; speedup 1.0000x reference)
//
#include <hip/hip_runtime.h>
#include <cmath>

// ConvLSTM, two-phase:
//   Phase 1: xg = conv_same(x[:, ::-1], Wx) for ALL (b,t) in one big parallel
//            kernel (f32, 64 MiB in d_ws). Weights read via wave-uniform
//            global loads (scalar s_load path, no LDS).
//   Phase 2: 16 sequential step kernels: hg = conv_same(h_prev, Wh) + gates.
//            h lives in d_out (out[b,t-1] is h_prev), c in d_ws.
//
// x:  (B=8, T=16, C=16, H=128, W=128) f32
// Wx: (KH=4, KW=2, C=16, O=8) HWIO
// Wh: (KH=4, KW=2, F=2, O=8)
// out:(B, T, F=2, H, W) f32

constexpr int B_ = 8;
constexpr int T_ = 16;
constexpr int C_ = 16;
constexpr int F_ = 2;
constexpr int O_ = 8;      // 4*F gate channels
constexpr int H_ = 128;
constexpr int W_ = 128;
constexpr int HW_ = H_ * W_;
constexpr int KH_ = 4;
constexpr int KW_ = 2;
constexpr int PX_ = 4;     // pixels per thread in xg_kernel

__device__ __forceinline__ float hsig(float z) {
    return fminf(fmaxf(0.2f * z + 0.5f, 0.0f), 1.0f);
}

// tanh via fast exp; exact at +-inf saturation: 1 - 2/(e^{2x}+1)
__device__ __forceinline__ float ftanh(float x) {
    float e = __expf(2.0f * x);
    return fmaf(-2.0f, 1.0f / (e + 1.0f), 1.0f);
}

// ---------------- Phase 1: all-timestep x-conv ----------------
// grid: B*T*HW/PX threads; each thread computes PX=4 consecutive pixels
// (along W) for all 8 gate channels. xg layout: [t][b][o][h][w] f32.
__global__ __launch_bounds__(256) void xg_kernel(
    const float* __restrict__ x,
    const float* __restrict__ Wx,
    float* __restrict__ xg)
{
    int gid = blockIdx.x * 256 + threadIdx.x;      // B*T*HW/4 = 524288
    int bt  = gid >> 12;                            // HW/4 = 4096 threads per (b,t)
    int rem = gid & 4095;
    int oh  = rem >> 5;                             // 128 rows
    int ow4 = (rem & 31) << 2;                      // 32 quads per row

    int b    = bt >> 4;
    int trev = bt & 15;
    int t    = 15 - trev;                           // time reversal

    const float* xs = x + (size_t)bt * C_ * HW_;    // x[b][trev]

    float acc[PX_][O_];
    #pragma unroll
    for (int p = 0; p < PX_; ++p)
        #pragma unroll
        for (int o = 0; o < O_; ++o) acc[p][o] = 0.0f;

    bool cval = ow4 < (W_ - 4);                     // col ow4+4 in-bounds?

    #pragma unroll
    for (int kh = 0; kh < KH_; ++kh) {
        int ih  = oh + kh - 1;                      // pad_top = 1
        bool rv = (unsigned)ih < (unsigned)H_;
        int ihc = rv ? ih : 0;
        const float* xrow = xs + ihc * W_ + ow4;
        const float* wb   = Wx + kh * (KW_ * C_ * O_);   // kh*256, uniform
        #pragma unroll
        for (int c = 0; c < C_; ++c) {
            float4 v = *reinterpret_cast<const float4*>(xrow + c * HW_);
            float  x4 = cval ? xrow[c * HW_ + 4] : 0.0f;
            float xv[PX_ + 1];
            xv[0] = rv ? v.x : 0.0f;
            xv[1] = rv ? v.y : 0.0f;
            xv[2] = rv ? v.z : 0.0f;
            xv[3] = rv ? v.w : 0.0f;
            xv[4] = rv ? x4  : 0.0f;
            #pragma unroll
            for (int o = 0; o < O_; ++o) {
                float w0 = wb[c * O_ + o];               // kw=0, uniform -> SGPR
                float w1 = wb[C_ * O_ + c * O_ + o];     // kw=1, uniform -> SGPR
                #pragma unroll
                for (int p = 0; p < PX_; ++p) {
                    acc[p][o] = fmaf(xv[p],     w0, acc[p][o]);
                    acc[p][o] = fmaf(xv[p + 1], w1, acc[p][o]);
                }
            }
        }
    }

    float* dst = xg + (size_t)(t * B_ + b) * O_ * HW_ + oh * W_ + ow4;
    #pragma unroll
    for (int o = 0; o < O_; ++o) {
        *reinterpret_cast<float4*>(dst + o * HW_) =
            make_float4(acc[0][o], acc[1][o], acc[2][o], acc[3][o]);
    }
}

// ---------------- Phase 2: sequential LSTM step ----------------
__global__ __launch_bounds__(256) void step_kernel(
    const float* __restrict__ xg,
    const float* __restrict__ Wh,
    float* __restrict__ out,
    float* __restrict__ cbuf,
    int t)
{
    int gid = blockIdx.x * 256 + threadIdx.x;   // B*HW = 131072
    int b   = gid >> 14;
    int pix = gid & (HW_ - 1);
    int oh  = pix >> 7;
    int ow  = pix & (W_ - 1);

    // start from xg_t
    const float* xgp = xg + (size_t)(t * B_ + b) * O_ * HW_ + pix;
    float acc[O_];
    #pragma unroll
    for (int o = 0; o < O_; ++o) acc[o] = xgp[o * HW_];

    bool cv  = (ow + 1) < W_;
    int  co1 = cv ? 1 : 0;

    if (t > 0) {
        const float* hs = out + (size_t)(b * T_ + (t - 1)) * F_ * HW_;
        #pragma unroll
        for (int kh = 0; kh < KH_; ++kh) {
            int ih  = oh + kh - 1;
            bool rv = (unsigned)ih < (unsigned)H_;
            int ihc = rv ? ih : 0;
            const float* hrow  = hs + ihc * W_ + ow;
            const float* wb = Wh + kh * (KW_ * F_ * O_);   // kh*32, uniform
            #pragma unroll
            for (int f = 0; f < F_; ++f) {
                float h0 = hrow[f * HW_];
                float h1 = hrow[f * HW_ + co1];
                h0 = rv ? h0 : 0.0f;
                h1 = (rv && cv) ? h1 : 0.0f;
                #pragma unroll
                for (int o = 0; o < O_; ++o) {
                    acc[o] = fmaf(h0, wb[f * O_ + o], acc[o]);
                    acc[o] = fmaf(h1, wb[F_ * O_ + f * O_ + o], acc[o]);
                }
            }
        }
    }

    // gates: [0,1]=i, [2,3]=f, [4,5]=g, [6,7]=o
    size_t cidx = (size_t)b * F_ * HW_ + pix;
    float cp0 = 0.0f, cp1 = 0.0f;
    if (t > 0) { cp0 = cbuf[cidx]; cp1 = cbuf[cidx + HW_]; }

    float gi0 = hsig(acc[0]);
    float gi1 = hsig(acc[1]);
    float gf0 = hsig(acc[2]);
    float gf1 = hsig(acc[3]);
    float gg0 = ftanh(acc[4]);
    float gg1 = ftanh(acc[5]);
    float go0 = hsig(acc[6]);
    float go1 = hsig(acc[7]);

    float cn0 = gf0 * cp0 + gi0 * gg0;
    float cn1 = gf1 * cp1 + gi1 * gg1;
    cbuf[cidx]       = cn0;
    cbuf[cidx + HW_] = cn1;

    size_t oidx = (size_t)(b * T_ + t) * F_ * HW_ + pix;
    out[oidx]       = go0 * ftanh(cn0);
    out[oidx + HW_] = go1 * ftanh(cn1);
}

extern "C" void kernel_launch(void* const* d_in, const int* in_sizes, int n_in,
                              void* d_out, int out_size, void* d_ws, size_t ws_size,
                              hipStream_t stream) {
    const float* x  = (const float*)d_in[0];
    const float* Wx = (const float*)d_in[1];
    const float* Wh = (const float*)d_in[2];
    float* out  = (float*)d_out;

    float* xg   = (float*)d_ws;                               // 64 MiB
    float* cbuf = (float*)((char*)d_ws + (size_t)64 * 1024 * 1024 + 1024); // 1 MiB

    int xg_blocks = (B_ * T_ * HW_ / PX_) / 256;   // 2048
    xg_kernel<<<xg_blocks, 256, 0, stream>>>(x, Wx, xg);

    int blocks = (B_ * HW_) / 256;                 // 512
    for (int t = 0; t < T_; ++t) {
        step_kernel<<<blocks, 256, 0, stream>>>(xg, Wh, out, cbuf, t);
    }
}

// Round 3
// 160.879 us; speedup vs baseline: 1.7294x; 1.7294x over previous
//
#include <hip/hip_runtime.h>
#include <cmath>

// ConvLSTM, two-phase:
//   Phase 1: xg = conv_same(x[:, ::-1], Wx) for ALL (b,t), one parallel kernel.
//            Register-blocked 4px x 8o per thread; kh/c-pair loops NOT unrolled
//            so only 32 wave-uniform weights are live per iter (-> SGPRs).
//            Interior row-blocks take a select-free path.
//   Phase 2: 16 sequential step kernels (h-conv + gates), ~BW-floor already.
//
// x:  (B=8, T=16, C=16, H=128, W=128) f32
// Wx: (KH=4, KW=2, C=16, O=8) HWIO     idx = kh*256 + kw*128 + c*8 + o
// Wh: (KH=4, KW=2, F=2, O=8)
// out:(B, T, F=2, H, W) f32
// ws: xg (64 MiB) + c-state (1 MiB)

constexpr int B_ = 8;
constexpr int T_ = 16;
constexpr int C_ = 16;
constexpr int F_ = 2;
constexpr int O_ = 8;
constexpr int H_ = 128;
constexpr int W_ = 128;
constexpr int HW_ = H_ * W_;
constexpr int KH_ = 4;
constexpr int KW_ = 2;
constexpr int PX_ = 4;

__device__ __forceinline__ float hsig(float z) {
    return fminf(fmaxf(0.2f * z + 0.5f, 0.0f), 1.0f);
}

__device__ __forceinline__ float ftanh(float x) {
    float e = __expf(2.0f * x);
    return fmaf(-2.0f, 1.0f / (e + 1.0f), 1.0f);
}

// ---------------- Phase 1 conv body ----------------
template<bool CHECK>
__device__ __forceinline__ void conv_body(
    const float* __restrict__ xs,    // x[b][trev] base
    const float* __restrict__ Wx,
    float acc[PX_][O_],
    int oh, int ow4, bool cval, int co4)
{
    #pragma unroll 1
    for (int kh = 0; kh < KH_; ++kh) {
        int ih  = oh + kh - 1;                    // pad_top = 1
        bool rv = true;
        int ihc = ih;
        if (CHECK) {
            rv  = (unsigned)ih < (unsigned)H_;
            ihc = rv ? ih : 0;
        }
        const float* xrow = xs + ihc * W_ + ow4;
        const float* wk   = Wx + kh * (KW_ * C_ * O_);   // kh*256
        #pragma unroll 1
        for (int cc = 0; cc < C_ / 2; ++cc) {            // 2 channels per iter
            const float* xr = xrow + cc * 2 * HW_;
            const float* wc = wk + cc * 2 * O_;
            #pragma unroll
            for (int u = 0; u < 2; ++u) {
                float4 v  = *reinterpret_cast<const float4*>(xr + u * HW_);
                float  t4 = xr[u * HW_ + co4];           // clamped addr (in-bounds)
                float xv0 = v.x, xv1 = v.y, xv2 = v.z, xv3 = v.w;
                float xv4 = cval ? t4 : 0.0f;
                if (CHECK) {
                    xv0 = rv ? xv0 : 0.0f;
                    xv1 = rv ? xv1 : 0.0f;
                    xv2 = rv ? xv2 : 0.0f;
                    xv3 = rv ? xv3 : 0.0f;
                    xv4 = rv ? xv4 : 0.0f;
                }
                #pragma unroll
                for (int o = 0; o < O_; ++o) {
                    float w0 = wc[u * O_ + o];                   // kw=0 (uniform)
                    float w1 = wc[C_ * O_ + u * O_ + o];         // kw=1 (uniform)
                    acc[0][o] = fmaf(xv0, w0, acc[0][o]);
                    acc[1][o] = fmaf(xv1, w0, acc[1][o]);
                    acc[2][o] = fmaf(xv2, w0, acc[2][o]);
                    acc[3][o] = fmaf(xv3, w0, acc[3][o]);
                    acc[0][o] = fmaf(xv1, w1, acc[0][o]);
                    acc[1][o] = fmaf(xv2, w1, acc[1][o]);
                    acc[2][o] = fmaf(xv3, w1, acc[2][o]);
                    acc[3][o] = fmaf(xv4, w1, acc[3][o]);
                }
            }
        }
    }
}

// grid: B*T*HW/4 threads; thread = 4 consecutive w-pixels, all 8 gate chans.
// xg layout: [t][b][o][h][w] f32.
__global__ __launch_bounds__(256, 4) void xg_kernel(
    const float* __restrict__ x,
    const float* __restrict__ Wx,
    float* __restrict__ xg)
{
    int gid = blockIdx.x * 256 + threadIdx.x;      // 524288 total
    int bt  = gid >> 12;                            // 4096 threads per (b,t)
    int rem = gid & 4095;
    int oh  = rem >> 5;
    int ow4 = (rem & 31) << 2;

    int b    = bt >> 4;
    int trev = bt & 15;
    int t    = 15 - trev;

    const float* xs = x + (size_t)bt * C_ * HW_;

    float acc[PX_][O_];
    #pragma unroll
    for (int p = 0; p < PX_; ++p)
        #pragma unroll
        for (int o = 0; o < O_; ++o) acc[p][o] = 0.0f;

    bool cval = ow4 < (W_ - 4);
    int  co4  = cval ? 4 : 0;

    // block = 8 consecutive rows of one image; interior iff rows [1..125]
    int row0 = ((blockIdx.x * 256) & 4095) >> 5;
    if (row0 >= 1 && row0 <= 118) {
        conv_body<false>(xs, Wx, acc, oh, ow4, cval, co4);
    } else {
        conv_body<true>(xs, Wx, acc, oh, ow4, cval, co4);
    }

    float* dst = xg + (size_t)(t * B_ + b) * O_ * HW_ + oh * W_ + ow4;
    #pragma unroll
    for (int o = 0; o < O_; ++o) {
        *reinterpret_cast<float4*>(dst + o * HW_) =
            make_float4(acc[0][o], acc[1][o], acc[2][o], acc[3][o]);
    }
}

// ---------------- Phase 2: sequential LSTM step ----------------
__global__ __launch_bounds__(256) void step_kernel(
    const float* __restrict__ xg,
    const float* __restrict__ Wh,
    float* __restrict__ out,
    float* __restrict__ cbuf,
    int t)
{
    int gid = blockIdx.x * 256 + threadIdx.x;   // B*HW = 131072
    int b   = gid >> 14;
    int pix = gid & (HW_ - 1);
    int oh  = pix >> 7;
    int ow  = pix & (W_ - 1);

    const float* xgp = xg + (size_t)(t * B_ + b) * O_ * HW_ + pix;
    float acc[O_];
    #pragma unroll
    for (int o = 0; o < O_; ++o) acc[o] = xgp[o * HW_];

    bool cv  = (ow + 1) < W_;
    int  co1 = cv ? 1 : 0;

    if (t > 0) {
        const float* hs = out + (size_t)(b * T_ + (t - 1)) * F_ * HW_;
        #pragma unroll
        for (int kh = 0; kh < KH_; ++kh) {
            int ih  = oh + kh - 1;
            bool rv = (unsigned)ih < (unsigned)H_;
            int ihc = rv ? ih : 0;
            const float* hrow = hs + ihc * W_ + ow;
            const float* wb   = Wh + kh * (KW_ * F_ * O_);
            #pragma unroll
            for (int f = 0; f < F_; ++f) {
                float h0 = hrow[f * HW_];
                float h1 = hrow[f * HW_ + co1];
                h0 = rv ? h0 : 0.0f;
                h1 = (rv && cv) ? h1 : 0.0f;
                #pragma unroll
                for (int o = 0; o < O_; ++o) {
                    acc[o] = fmaf(h0, wb[f * O_ + o], acc[o]);
                    acc[o] = fmaf(h1, wb[F_ * O_ + f * O_ + o], acc[o]);
                }
            }
        }
    }

    size_t cidx = (size_t)b * F_ * HW_ + pix;
    float cp0 = 0.0f, cp1 = 0.0f;
    if (t > 0) { cp0 = cbuf[cidx]; cp1 = cbuf[cidx + HW_]; }

    float gi0 = hsig(acc[0]);
    float gi1 = hsig(acc[1]);
    float gf0 = hsig(acc[2]);
    float gf1 = hsig(acc[3]);
    float gg0 = ftanh(acc[4]);
    float gg1 = ftanh(acc[5]);
    float go0 = hsig(acc[6]);
    float go1 = hsig(acc[7]);

    float cn0 = gf0 * cp0 + gi0 * gg0;
    float cn1 = gf1 * cp1 + gi1 * gg1;
    cbuf[cidx]       = cn0;
    cbuf[cidx + HW_] = cn1;

    size_t oidx = (size_t)(b * T_ + t) * F_ * HW_ + pix;
    out[oidx]       = go0 * ftanh(cn0);
    out[oidx + HW_] = go1 * ftanh(cn1);
}

extern "C" void kernel_launch(void* const* d_in, const int* in_sizes, int n_in,
                              void* d_out, int out_size, void* d_ws, size_t ws_size,
                              hipStream_t stream) {
    const float* x  = (const float*)d_in[0];
    const float* Wx = (const float*)d_in[1];
    const float* Wh = (const float*)d_in[2];
    float* out  = (float*)d_out;

    float* xg   = (float*)d_ws;                                            // 64 MiB
    float* cbuf = (float*)((char*)d_ws + (size_t)64 * 1024 * 1024 + 1024); // 1 MiB

    int xg_blocks = (B_ * T_ * HW_ / PX_) / 256;   // 2048
    xg_kernel<<<xg_blocks, 256, 0, stream>>>(x, Wx, xg);

    int blocks = (B_ * HW_) / 256;                 // 512
    for (int t = 0; t < T_; ++t) {
        step_kernel<<<blocks, 256, 0, stream>>>(xg, Wh, out, cbuf, t);
    }
}

// Round 5
// 128.180 us; speedup vs baseline: 2.1706x; 1.2551x over previous
//
#include <hip/hip_runtime.h>
#include <cmath>

// ConvLSTM, two-phase:
//   Phase 1: xg = conv_same(x[:, ::-1], Wx) for ALL (b,t), one parallel kernel.
//            c-outer / kh-inner register-blocked loop (4px x 8o per thread),
//            unroll-2 c loop for MLP, XCD-chunked block swizzle, nontemporal
//            xg stores (no L2 write-allocate).
//   Phase 2: 16 sequential step kernels (h-conv + gates), ~BW-floor already.
//
// x:  (B=8, T=16, C=16, H=128, W=128) f32
// Wx: (KH=4, KW=2, C=16, O=8) HWIO     idx = kh*256 + kw*128 + c*8 + o
// Wh: (KH=4, KW=2, F=2, O=8)
// out:(B, T, F=2, H, W) f32
// ws: xg (64 MiB, layout [t][b][o][h][w]) + c-state (1 MiB)

constexpr int B_ = 8;
constexpr int T_ = 16;
constexpr int C_ = 16;
constexpr int F_ = 2;
constexpr int O_ = 8;
constexpr int H_ = 128;
constexpr int W_ = 128;
constexpr int HW_ = H_ * W_;
constexpr int KH_ = 4;
constexpr int KW_ = 2;
constexpr int PX_ = 4;

typedef float fv4 __attribute__((ext_vector_type(4)));

__device__ __forceinline__ float hsig(float z) {
    return fminf(fmaxf(0.2f * z + 0.5f, 0.0f), 1.0f);
}

__device__ __forceinline__ float ftanh(float x) {
    float e = __expf(2.0f * x);
    return fmaf(-2.0f, 1.0f / (e + 1.0f), 1.0f);
}

// ---------------- Phase 1 conv body: c outer, kh inner ----------------
template<bool CHECK>
__device__ __forceinline__ void conv_body(
    const float* __restrict__ xs,    // x[b][trev] image base
    const float* __restrict__ Wx,
    float acc[PX_][O_],
    int oh, int ow4, bool cval, int co4)
{
    #pragma unroll 2
    for (int c = 0; c < C_; ++c) {
        const float* xc = xs + c * HW_ + ow4;
        float xv[KH_][PX_ + 1];
        // load 4 input rows (ih = oh-1 .. oh+2), 5 values each
        #pragma unroll
        for (int kh = 0; kh < KH_; ++kh) {
            int ih  = oh + kh - 1;                 // pad_top = 1
            bool rv = true;
            int ihc = ih;
            if (CHECK) {
                rv  = (unsigned)ih < (unsigned)H_;
                ihc = rv ? ih : 0;
            }
            const float* r = xc + ihc * W_;
            fv4   v  = *reinterpret_cast<const fv4*>(r);
            float t4 = r[co4];                     // clamped addr, in-bounds
            xv[kh][0] = v.x;
            xv[kh][1] = v.y;
            xv[kh][2] = v.z;
            xv[kh][3] = v.w;
            xv[kh][4] = cval ? t4 : 0.0f;
            if (CHECK) {
                #pragma unroll
                for (int p = 0; p < PX_ + 1; ++p)
                    xv[kh][p] = rv ? xv[kh][p] : 0.0f;
            }
        }
        // apply all kh taps (weights wave-uniform -> SGPR operands)
        #pragma unroll
        for (int kh = 0; kh < KH_; ++kh) {
            const float* wp = Wx + kh * (KW_ * C_ * O_) + c * O_;
            #pragma unroll
            for (int o = 0; o < O_; ++o) {
                float w0 = wp[o];             // kw = 0
                float w1 = wp[C_ * O_ + o];   // kw = 1
                acc[0][o] = fmaf(xv[kh][0], w0, acc[0][o]);
                acc[1][o] = fmaf(xv[kh][1], w0, acc[1][o]);
                acc[2][o] = fmaf(xv[kh][2], w0, acc[2][o]);
                acc[3][o] = fmaf(xv[kh][3], w0, acc[3][o]);
                acc[0][o] = fmaf(xv[kh][1], w1, acc[0][o]);
                acc[1][o] = fmaf(xv[kh][2], w1, acc[1][o]);
                acc[2][o] = fmaf(xv[kh][3], w1, acc[2][o]);
                acc[3][o] = fmaf(xv[kh][4], w1, acc[3][o]);
            }
        }
    }
}

// grid: 2048 blocks x 256 thr; thread = 4 consecutive w-pixels, all 8 chans.
__global__ __launch_bounds__(256, 4) void xg_kernel(
    const float* __restrict__ x,
    const float* __restrict__ Wx,
    float* __restrict__ xg)
{
    // XCD-chunked swizzle (8 XCDs, 2048 % 8 == 0 -> bijective):
    // chunks of 256 consecutive work-ids land on one XCD.
    int wid = (blockIdx.x & 7) * 256 + (blockIdx.x >> 3);

    int gid = wid * 256 + threadIdx.x;             // 524288 total
    int bt  = gid >> 12;                            // 4096 threads per (b,t)
    int rem = gid & 4095;
    int oh  = rem >> 5;
    int ow4 = (rem & 31) << 2;

    int b    = bt >> 4;
    int trev = bt & 15;
    int t    = 15 - trev;

    const float* xs = x + (size_t)bt * C_ * HW_;

    float acc[PX_][O_];
    #pragma unroll
    for (int p = 0; p < PX_; ++p)
        #pragma unroll
        for (int o = 0; o < O_; ++o) acc[p][o] = 0.0f;

    bool cval = ow4 < (W_ - 4);
    int  co4  = cval ? 4 : 0;

    // block = 8 consecutive rows of one image; needs input rows row0-1..row0+9
    int row0 = ((wid * 256) & 4095) >> 5;
    if (row0 >= 1 && row0 <= 118) {
        conv_body<false>(xs, Wx, acc, oh, ow4, cval, co4);
    } else {
        conv_body<true>(xs, Wx, acc, oh, ow4, cval, co4);
    }

    float* dst = xg + (size_t)(t * B_ + b) * O_ * HW_ + oh * W_ + ow4;
    #pragma unroll
    for (int o = 0; o < O_; ++o) {
        fv4 s;
        s.x = acc[0][o]; s.y = acc[1][o]; s.z = acc[2][o]; s.w = acc[3][o];
        __builtin_nontemporal_store(s, reinterpret_cast<fv4*>(dst + o * HW_));
    }
}

// ---------------- Phase 2: sequential LSTM step ----------------
__global__ __launch_bounds__(256) void step_kernel(
    const float* __restrict__ xg,
    const float* __restrict__ Wh,
    float* __restrict__ out,
    float* __restrict__ cbuf,
    int t)
{
    int gid = blockIdx.x * 256 + threadIdx.x;   // B*HW = 131072
    int b   = gid >> 14;
    int pix = gid & (HW_ - 1);
    int oh  = pix >> 7;
    int ow  = pix & (W_ - 1);

    const float* xgp = xg + (size_t)(t * B_ + b) * O_ * HW_ + pix;
    float acc[O_];
    #pragma unroll
    for (int o = 0; o < O_; ++o)
        acc[o] = __builtin_nontemporal_load(xgp + o * HW_);

    bool cv  = (ow + 1) < W_;
    int  co1 = cv ? 1 : 0;

    if (t > 0) {
        const float* hs = out + (size_t)(b * T_ + (t - 1)) * F_ * HW_;
        #pragma unroll
        for (int kh = 0; kh < KH_; ++kh) {
            int ih  = oh + kh - 1;
            bool rv = (unsigned)ih < (unsigned)H_;
            int ihc = rv ? ih : 0;
            const float* hrow = hs + ihc * W_ + ow;
            const float* wb   = Wh + kh * (KW_ * F_ * O_);
            #pragma unroll
            for (int f = 0; f < F_; ++f) {
                float h0 = hrow[f * HW_];
                float h1 = hrow[f * HW_ + co1];
                h0 = rv ? h0 : 0.0f;
                h1 = (rv && cv) ? h1 : 0.0f;
                #pragma unroll
                for (int o = 0; o < O_; ++o) {
                    acc[o] = fmaf(h0, wb[f * O_ + o], acc[o]);
                    acc[o] = fmaf(h1, wb[F_ * O_ + f * O_ + o], acc[o]);
                }
            }
        }
    }

    size_t cidx = (size_t)b * F_ * HW_ + pix;
    float cp0 = 0.0f, cp1 = 0.0f;
    if (t > 0) { cp0 = cbuf[cidx]; cp1 = cbuf[cidx + HW_]; }

    float gi0 = hsig(acc[0]);
    float gi1 = hsig(acc[1]);
    float gf0 = hsig(acc[2]);
    float gf1 = hsig(acc[3]);
    float gg0 = ftanh(acc[4]);
    float gg1 = ftanh(acc[5]);
    float go0 = hsig(acc[6]);
    float go1 = hsig(acc[7]);

    float cn0 = gf0 * cp0 + gi0 * gg0;
    float cn1 = gf1 * cp1 + gi1 * gg1;
    cbuf[cidx]       = cn0;
    cbuf[cidx + HW_] = cn1;

    size_t oidx = (size_t)(b * T_ + t) * F_ * HW_ + pix;
    out[oidx]       = go0 * ftanh(cn0);
    out[oidx + HW_] = go1 * ftanh(cn1);
}

extern "C" void kernel_launch(void* const* d_in, const int* in_sizes, int n_in,
                              void* d_out, int out_size, void* d_ws, size_t ws_size,
                              hipStream_t stream) {
    const float* x  = (const float*)d_in[0];
    const float* Wx = (const float*)d_in[1];
    const float* Wh = (const float*)d_in[2];
    float* out  = (float*)d_out;

    float* xg   = (float*)d_ws;                                            // 64 MiB
    float* cbuf = (float*)((char*)d_ws + (size_t)64 * 1024 * 1024 + 1024); // 1 MiB

    int xg_blocks = (B_ * T_ * HW_ / PX_) / 256;   // 2048
    xg_kernel<<<xg_blocks, 256, 0, stream>>>(x, Wx, xg);

    int blocks = (B_ * HW_) / 256;                 // 512
    for (int t = 0; t < T_; ++t) {
        step_kernel<<<blocks, 256, 0, stream>>>(xg, Wh, out, cbuf, t);
    }
}